// Round 2
// baseline (5224.424 us; speedup 1.0000x reference)
//
#include <hip/hip_runtime.h>

// Problem constants (fixed by setup_inputs)
#define BB 4
#define Q 75
#define WAY 5
#define SHOT 5
#define HW 100
#define D 640
#define M 500          // shot*HW
#define QROWS 7500     // Q*HW
#define NDQ 30000      // BB*QROWS query descriptors
#define NDS 10000      // BB*WAY*M support descriptors

// ws layout (float offsets)
#define WS_QINV 0
#define WS_SINV 30000
#define WS_QMEAN 40000     // BB*Q*D = 192000
#define WS_PROTO 232000    // BB*WAY*D = 12800
#define WS_FEAT 244800     // BB*Q*10 = 3000

// ---------------- kernel 1: inverse L2 norms of every local descriptor ---------
__global__ void norms_kernel(const float* __restrict__ xq, const float* __restrict__ xs,
                             float* __restrict__ ws) {
    int wid  = (int)((blockIdx.x * blockDim.x + threadIdx.x) >> 6);
    int lane = threadIdx.x & 63;
    if (wid >= NDQ + NDS) return;
    const float* p = (wid < NDQ) ? (xq + (size_t)wid * D)
                                 : (xs + (size_t)(wid - NDQ) * D);
    float s = 0.f;
    #pragma unroll
    for (int j = 0; j < D; j += 64) { float v = p[j + lane]; s += v * v; }
    for (int off = 32; off; off >>= 1) s += __shfl_down(s, off);
    if (lane == 0) {
        float inv = rsqrtf(s);
        if (wid < NDQ) ws[WS_QINV + wid] = inv;
        else           ws[WS_SINV + (wid - NDQ)] = inv;
    }
}

// ---------------- kernel 2: query_mean (over HW) and proto (over shot*HW) ------
__global__ void means_kernel(const float* __restrict__ xq, const float* __restrict__ xs,
                             float* __restrict__ ws) {
    __shared__ float inv[M];
    int bid = blockIdx.x;
    if (bid < BB * Q) {
        for (int i = threadIdx.x; i < HW; i += blockDim.x) inv[i] = ws[WS_QINV + bid * HW + i];
        __syncthreads();
        const float* base = xq + (size_t)bid * HW * D;
        for (int d = threadIdx.x; d < D; d += blockDim.x) {
            float s = 0.f;
            for (int h = 0; h < HW; ++h) s += base[(size_t)h * D + d] * inv[h];
            ws[WS_QMEAN + bid * D + d] = s * (1.f / HW);
        }
    } else {
        int bw = bid - BB * Q; // 0..19
        for (int i = threadIdx.x; i < M; i += blockDim.x) inv[i] = ws[WS_SINV + bw * M + i];
        __syncthreads();
        const float* base = xs + (size_t)bw * M * D;
        for (int d = threadIdx.x; d < D; d += blockDim.x) {
            float s = 0.f;
            for (int m = 0; m < M; ++m) s += base[(size_t)m * D + d] * inv[m];
            ws[WS_PROTO + bw * D + d] = s * (1.f / M);
        }
    }
}

// ---------------- kernel 3: cosine-prototype logits + zero-init sim slots ------
__global__ void cos_kernel(float* __restrict__ ws) {
    int idx  = (int)((blockIdx.x * blockDim.x + threadIdx.x) >> 6); // (b,q,w) wave id
    int lane = threadIdx.x & 63;
    if (idx >= BB * Q * WAY) return;
    int w = idx % WAY; int bq = idx / WAY; int b = bq / Q;
    const float* qm = ws + WS_QMEAN + bq * D;
    const float* pr = ws + WS_PROTO + (b * WAY + w) * D;
    float s = 0.f;
    #pragma unroll
    for (int j = 0; j < D; j += 64) s += qm[j + lane] * pr[j + lane];
    for (int off = 32; off; off >>= 1) s += __shfl_down(s, off);
    if (lane == 0) {
        ws[WS_FEAT + bq * 10 + w]     = s;
        ws[WS_FEAT + bq * 10 + 5 + w] = 0.f;   // sim slot zero-init (ws is poisoned)
    }
}

// ---------------- kernel 4: fused cosine-GEMM + streaming top-5 ----------------
#define RT 32       // rows (flattened q*HW) per block
#define MC 128      // support-descriptor chunk
#define KT 32       // K tile
#define NRT 235     // ceil(7500/32)
#define ASTR 36     // LDS strides (floats): 36 keeps b128 reads conflict-free
#define BSTR 36
#define CSTR 129    // odd stride -> conflict-free column scan

__global__ __launch_bounds__(256) void dn4_kernel(const float* __restrict__ xq,
                                                  const float* __restrict__ xs,
                                                  float* __restrict__ ws) {
    __shared__ float As[RT * ASTR];
    __shared__ float Bs[MC * BSTR];
    __shared__ float Cs[RT * CSTR];

    int bid = blockIdx.x;
    int rt = bid % NRT; int bw = bid / NRT;
    int w = bw % WAY;   int b  = bw / WAY;
    int tid = threadIdx.x;
    int tr = tid & 7;          // row group for compute (rows tr+8j)
    int tc = tid >> 3;         // col group (cols tc+32i)
    int srow = tid >> 3;       // staging row
    int sc4  = (tid & 7) * 4;  // staging float offset

    const float* qinv = ws + WS_QINV;
    const float* sinv = ws + WS_SINV;

    // running top-5 (descending) for the row owned by thread tid (tid < RT)
    float t0 = -1e30f, t1 = -1e30f, t2 = -1e30f, t3 = -1e30f, t4 = -1e30f;

    for (int mc = 0; mc < 4; ++mc) {
        int m0 = mc * MC;
        float acc[4][4];
        #pragma unroll
        for (int j = 0; j < 4; ++j)
            #pragma unroll
            for (int i = 0; i < 4; ++i) acc[j][i] = 0.f;

        for (int kt = 0; kt < D / KT; ++kt) {
            int k0 = kt * KT;
            // stage A: 32 rows x 32 cols (normalized on the fly)
            {
                int grow = rt * RT + srow;
                float4 v = make_float4(0.f, 0.f, 0.f, 0.f);
                if (grow < QROWS) {
                    const float* p = xq + ((size_t)(b * QROWS + grow)) * D + k0 + sc4;
                    v = *(const float4*)p;
                    float s = qinv[b * QROWS + grow];
                    v.x *= s; v.y *= s; v.z *= s; v.w *= s;
                }
                *(float4*)&As[srow * ASTR + sc4] = v;
            }
            // stage B: 128 rows x 32 cols
            #pragma unroll
            for (int jj = 0; jj < 4; ++jj) {
                int brow = srow + 32 * jj;
                int m = m0 + brow;
                float4 v = make_float4(0.f, 0.f, 0.f, 0.f);
                if (m < M) {
                    const float* p = xs + ((size_t)((b * WAY + w) * M + m)) * D + k0 + sc4;
                    v = *(const float4*)p;
                    float s = sinv[(b * WAY + w) * M + m];
                    v.x *= s; v.y *= s; v.z *= s; v.w *= s;
                }
                *(float4*)&Bs[brow * BSTR + sc4] = v;
            }
            __syncthreads();
            #pragma unroll
            for (int kk = 0; kk < KT; kk += 4) {
                float4 a[4], bbv[4];
                #pragma unroll
                for (int j = 0; j < 4; ++j) a[j]   = *(float4*)&As[(tr + 8 * j) * ASTR + kk];
                #pragma unroll
                for (int i = 0; i < 4; ++i) bbv[i] = *(float4*)&Bs[(tc + 32 * i) * BSTR + kk];
                #pragma unroll
                for (int j = 0; j < 4; ++j)
                    #pragma unroll
                    for (int i = 0; i < 4; ++i)
                        acc[j][i] += a[j].x * bbv[i].x + a[j].y * bbv[i].y
                                   + a[j].z * bbv[i].z + a[j].w * bbv[i].w;
            }
            __syncthreads();
        }
        // stage C tile to LDS for the per-row scan
        #pragma unroll
        for (int j = 0; j < 4; ++j)
            #pragma unroll
            for (int i = 0; i < 4; ++i)
                Cs[(tr + 8 * j) * CSTR + (tc + 32 * i)] = acc[j][i];
        __syncthreads();
        // per-row top-5 update (owner thread keeps top5 in registers)
        if (tid < RT) {
            int cmax = M - m0; if (cmax > MC) cmax = MC;
            for (int c = 0; c < cmax; ++c) {
                float v = Cs[tid * CSTR + c];
                if (v > t4) {
                    t4 = v;
                    if (t4 > t3) { float tmp = t3; t3 = t4; t4 = tmp; }
                    if (t3 > t2) { float tmp = t2; t2 = t3; t3 = tmp; }
                    if (t2 > t1) { float tmp = t1; t1 = t2; t2 = tmp; }
                    if (t1 > t0) { float tmp = t0; t0 = t1; t1 = tmp; }
                }
            }
        }
        __syncthreads();
    }
    if (tid < RT) {
        int grow = rt * RT + tid;
        if (grow < QROWS) {
            int q = grow / HW;
            atomicAdd(&ws[WS_FEAT + (b * Q + q) * 10 + 5 + w],
                      (t0 + t1 + t2 + t3 + t4) * (1.f / M));
        }
    }
}

// ---------------- kernel 5: BatchNorm (training stats over q) + dilated conv ---
__global__ void bn_conv_kernel(const float* __restrict__ gamma, const float* __restrict__ beta,
                               const float* __restrict__ convw, const float* __restrict__ wsr,
                               float* __restrict__ out) {
    __shared__ float mu[10], rstd[10];
    int b = blockIdx.x;
    const float* feat = wsr + WS_FEAT + b * Q * 10;
    int t = threadIdx.x;
    if (t < 10) {
        float s = 0.f;
        for (int q = 0; q < Q; ++q) s += feat[q * 10 + t];
        float m = s / Q;
        float ss = 0.f;
        for (int q = 0; q < Q; ++q) { float d = feat[q * 10 + t] - m; ss += d * d; }
        mu[t] = m;
        rstd[t] = rsqrtf(ss / Q + 1e-5f);   // biased var, two-pass (avoids cancellation)
    }
    __syncthreads();
    if (t < Q * WAY) {
        int q = t / WAY, j = t % WAY;
        float bn0 = (feat[q * 10 + j]     - mu[j])     * rstd[j]     * gamma[j]     + beta[j];
        float bn1 = (feat[q * 10 + 5 + j] - mu[5 + j]) * rstd[5 + j] * gamma[5 + j] + beta[5 + j];
        out[(b * Q + q) * WAY + j] = convw[0] * bn0 + convw[1] * bn1;
    }
}

extern "C" void kernel_launch(void* const* d_in, const int* in_sizes, int n_in,
                              void* d_out, int out_size, void* d_ws, size_t ws_size,
                              hipStream_t stream) {
    const float* xq    = (const float*)d_in[0];
    const float* xs    = (const float*)d_in[1];
    const float* gamma = (const float*)d_in[2];
    const float* beta  = (const float*)d_in[3];
    const float* convw = (const float*)d_in[4];
    float* ws  = (float*)d_ws;
    float* out = (float*)d_out;

    // 40000 descriptor norms, one wave each, 4 waves/block -> 10000 blocks
    norms_kernel<<<(NDQ + NDS + 3) / 4, 256, 0, stream>>>(xq, xs, ws);
    means_kernel<<<BB * Q + BB * WAY, 256, 0, stream>>>(xq, xs, ws);
    cos_kernel<<<(BB * Q * WAY + 3) / 4, 256, 0, stream>>>(ws);
    dn4_kernel<<<BB * WAY * NRT, 256, 0, stream>>>(xq, xs, ws);
    bn_conv_kernel<<<BB, 384, 0, stream>>>(gamma, beta, convw, ws, out);
}

// Round 3
// 915.853 us; speedup vs baseline: 5.7044x; 5.7044x over previous
//
#include <hip/hip_runtime.h>

// Problem constants (fixed by setup_inputs)
#define BB 4
#define Q 75
#define WAY 5
#define HW 100
#define D 640
#define M 500          // shot*HW
#define QROWS 7500     // Q*HW
#define NDQ 30000      // BB*QROWS query descriptors
#define NDS 10000      // BB*WAY*M support descriptors

// ws layout (float offsets)
#define WS_QINV 0
#define WS_SINV 30000
#define WS_QMEAN 40000     // BB*Q*D = 192000
#define WS_PROTO 232000    // BB*WAY*D = 12800
#define WS_FEAT 244800     // BB*Q*10 = 3000

using short8  = __attribute__((ext_vector_type(8))) short;
using short4v = __attribute__((ext_vector_type(4))) short;
using float4v = __attribute__((ext_vector_type(4))) float;

// ---------------- kernel 1: inverse L2 norms of every local descriptor ---------
__global__ void norms_kernel(const float* __restrict__ xq, const float* __restrict__ xs,
                             float* __restrict__ ws) {
    int wid  = (int)((blockIdx.x * blockDim.x + threadIdx.x) >> 6);
    int lane = threadIdx.x & 63;
    if (wid >= NDQ + NDS) return;
    const float* p = (wid < NDQ) ? (xq + (size_t)wid * D)
                                 : (xs + (size_t)(wid - NDQ) * D);
    float s = 0.f;
    #pragma unroll
    for (int j = 0; j < D; j += 64) { float v = p[j + lane]; s += v * v; }
    for (int off = 32; off; off >>= 1) s += __shfl_down(s, off);
    if (lane == 0) {
        float inv = rsqrtf(s);
        if (wid < NDQ) ws[WS_QINV + wid] = inv;
        else           ws[WS_SINV + (wid - NDQ)] = inv;
    }
}

// ---------------- kernel 2: query_mean (over HW) and proto (over shot*HW) ------
__global__ void means_kernel(const float* __restrict__ xq, const float* __restrict__ xs,
                             float* __restrict__ ws) {
    __shared__ float inv[M];
    int bid = blockIdx.x;
    if (bid < BB * Q) {
        for (int i = threadIdx.x; i < HW; i += blockDim.x) inv[i] = ws[WS_QINV + bid * HW + i];
        __syncthreads();
        const float* base = xq + (size_t)bid * HW * D;
        for (int d = threadIdx.x; d < D; d += blockDim.x) {
            float s = 0.f;
            for (int h = 0; h < HW; ++h) s += base[(size_t)h * D + d] * inv[h];
            ws[WS_QMEAN + bid * D + d] = s * (1.f / HW);
        }
    } else {
        int bw = bid - BB * Q; // 0..19
        for (int i = threadIdx.x; i < M; i += blockDim.x) inv[i] = ws[WS_SINV + bw * M + i];
        __syncthreads();
        const float* base = xs + (size_t)bw * M * D;
        for (int d = threadIdx.x; d < D; d += blockDim.x) {
            float s = 0.f;
            for (int m = 0; m < M; ++m) s += base[(size_t)m * D + d] * inv[m];
            ws[WS_PROTO + bw * D + d] = s * (1.f / M);
        }
    }
}

// ---------------- kernel 3: cosine-prototype logits + zero-init sim slots ------
__global__ void cos_kernel(float* __restrict__ ws) {
    int idx  = (int)((blockIdx.x * blockDim.x + threadIdx.x) >> 6); // (b,q,w) wave id
    int lane = threadIdx.x & 63;
    if (idx >= BB * Q * WAY) return;
    int w = idx % WAY; int bq = idx / WAY; int b = bq / Q;
    const float* qm = ws + WS_QMEAN + bq * D;
    const float* pr = ws + WS_PROTO + (b * WAY + w) * D;
    float s = 0.f;
    #pragma unroll
    for (int j = 0; j < D; j += 64) s += qm[j + lane] * pr[j + lane];
    for (int off = 32; off; off >>= 1) s += __shfl_down(s, off);
    if (lane == 0) {
        ws[WS_FEAT + bq * 10 + w]     = s;
        ws[WS_FEAT + bq * 10 + 5 + w] = 0.f;   // sim slot zero-init (ws is poisoned)
    }
}

// ---------------- kernel 4: MFMA split-bf16 GEMM + streaming top-5 -------------
// block: 128 rows (q*HW) x 128-col chunks of M, 4 waves in 2x2 (64x64 each).
// C = Ah*Bh + Ah*Bl + Al*Bh accumulated fp32 (split-bf16, ~2^-16 rel error).
#define BM 128
#define BNc 128
#define BK 32
#define NRT 59        // ceil(7500/128)
#define ASTRIDE 40    // shorts per row (32 + 8 pad)
#define CSTRIDE 65    // floats per row in scan buffer -> bank=(row+col)%32, 2-way free

__device__ __forceinline__ void split1(float v, unsigned short& h, unsigned short& l) {
    unsigned u = __float_as_uint(v);
    unsigned short hu = (unsigned short)(u >> 16);          // truncate to bf16
    float hf = __uint_as_float((unsigned)hu << 16);
    float lo = v - hf;                                       // exact residual
    unsigned short lu = (unsigned short)(__float_as_uint(lo) >> 16);
    h = hu; l = lu;
}

__device__ __forceinline__ void split_store(float4 v, float s, short* dh, short* dl) {
    unsigned short h0,h1,h2,h3,l0,l1,l2,l3;
    split1(v.x * s, h0, l0); split1(v.y * s, h1, l1);
    split1(v.z * s, h2, l2); split1(v.w * s, h3, l3);
    short4v hv, lv;
    hv[0]=(short)h0; hv[1]=(short)h1; hv[2]=(short)h2; hv[3]=(short)h3;
    lv[0]=(short)l0; lv[1]=(short)l1; lv[2]=(short)l2; lv[3]=(short)l3;
    *(short4v*)dh = hv;
    *(short4v*)dl = lv;
}

__global__ __launch_bounds__(256) void dn4_kernel(const float* __restrict__ xq,
                                                  const float* __restrict__ xs,
                                                  float* __restrict__ ws) {
    // LDS: staging tiles (40960 B) unioned with scan buffer (33280 B); inv caches after.
    __shared__ __align__(16) char smem[41984];
    short* Ah = (short*)smem;                  // 128*40*2 = 10240
    short* Al = (short*)(smem + 10240);
    short* Bh = (short*)(smem + 20480);
    short* Bl = (short*)(smem + 30720);
    float* Cs = (float*)smem;                  // union: 128*65*4 = 33280
    float* qinvL = (float*)(smem + 40960);     // 128 floats
    float* sinvL = (float*)(smem + 41472);     // 128 floats

    int bid = blockIdx.x;
    int rt = bid % NRT; int bw = bid / NRT;
    int w = bw % WAY;   int b  = bw / WAY;
    int tid  = threadIdx.x;
    int lane = tid & 63;
    int wave = tid >> 6;
    int wr = wave >> 1, wc = wave & 1;   // 2x2 wave grid over 128x128
    int lfree = lane & 15;               // free-dim index within 16
    int lq    = lane >> 4;               // quad -> k-group of 8

    if (tid < BM) {
        int grow = rt * BM + tid;
        qinvL[tid] = (grow < QROWS) ? ws[WS_QINV + b * QROWS + grow] : 0.f;
    }

    const size_t abase = (size_t)b * QROWS * D;
    const size_t bbase = (size_t)(b * WAY + w) * M * D;

    // running top-5 (descending) for row tid (tid < 128)
    float t0 = -1e30f, t1 = -1e30f, t2 = -1e30f, t3 = -1e30f, t4 = -1e30f;

    for (int mc = 0; mc < 4; ++mc) {
        int m0 = mc * BNc;
        if (tid < BM) {
            int m = m0 + tid;
            sinvL[tid] = (m < M) ? ws[WS_SINV + (b * WAY + w) * M + m] : 0.f;
        }
        float4v acc[4][4];
        #pragma unroll
        for (int jj = 0; jj < 4; ++jj)
            #pragma unroll
            for (int ii = 0; ii < 4; ++ii) {
                acc[jj][ii][0] = 0.f; acc[jj][ii][1] = 0.f;
                acc[jj][ii][2] = 0.f; acc[jj][ii][3] = 0.f;
            }
        __syncthreads();   // inv caches visible; prior scan reads done before restage

        for (int kt = 0; kt < D / BK; ++kt) {
            int k0 = kt * BK;
            // ---- stage A (128x32) and B (128x32), normalize + split to bf16 hi/lo
            #pragma unroll
            for (int rep = 0; rep < 4; ++rep) {
                int flat = rep * 256 + tid;
                int row  = flat >> 3;          // 0..127
                int c    = (flat & 7) * 4;     // 0,4,..,28
                int grow = rt * BM + row;
                float4 va = make_float4(0.f, 0.f, 0.f, 0.f);
                if (grow < QROWS) va = *(const float4*)(xq + abase + (size_t)grow * D + k0 + c);
                split_store(va, qinvL[row], &Ah[row * ASTRIDE + c], &Al[row * ASTRIDE + c]);
                int m = m0 + row;
                float4 vb = make_float4(0.f, 0.f, 0.f, 0.f);
                if (m < M) vb = *(const float4*)(xs + bbase + (size_t)m * D + k0 + c);
                split_store(vb, sinvL[row], &Bh[row * ASTRIDE + c], &Bl[row * ASTRIDE + c]);
            }
            __syncthreads();
            // ---- fragments: A[m=lane&15][k=quad*8+j], B[n=lane&15][k=quad*8+j]
            short8 ahf[4], alf[4], bhf[4], blf[4];
            #pragma unroll
            for (int jj = 0; jj < 4; ++jj) {
                int r = 64 * wr + 16 * jj + lfree;
                ahf[jj] = *(const short8*)&Ah[r * ASTRIDE + lq * 8];
                alf[jj] = *(const short8*)&Al[r * ASTRIDE + lq * 8];
            }
            #pragma unroll
            for (int ii = 0; ii < 4; ++ii) {
                int n = 64 * wc + 16 * ii + lfree;
                bhf[ii] = *(const short8*)&Bh[n * ASTRIDE + lq * 8];
                blf[ii] = *(const short8*)&Bl[n * ASTRIDE + lq * 8];
            }
            #pragma unroll
            for (int jj = 0; jj < 4; ++jj)
                #pragma unroll
                for (int ii = 0; ii < 4; ++ii) {
                    acc[jj][ii] = __builtin_amdgcn_mfma_f32_16x16x32_bf16(ahf[jj], bhf[ii], acc[jj][ii], 0, 0, 0);
                    acc[jj][ii] = __builtin_amdgcn_mfma_f32_16x16x32_bf16(ahf[jj], blf[ii], acc[jj][ii], 0, 0, 0);
                    acc[jj][ii] = __builtin_amdgcn_mfma_f32_16x16x32_bf16(alf[jj], bhf[ii], acc[jj][ii], 0, 0, 0);
                }
            __syncthreads();   // before next restage
        }

        // ---- scan in two 64-col halves (C/D layout: col=lane&15, row=quad*4+reg)
        #pragma unroll
        for (int ch = 0; ch < 2; ++ch) {
            if (wc == ch) {
                #pragma unroll
                for (int jj = 0; jj < 4; ++jj)
                    #pragma unroll
                    for (int ii = 0; ii < 4; ++ii) {
                        int rbase = 64 * wr + 16 * jj + lq * 4;
                        int col   = 16 * ii + lfree;
                        #pragma unroll
                        for (int r = 0; r < 4; ++r)
                            Cs[(rbase + r) * CSTRIDE + col] = acc[jj][ii][r];
                    }
            }
            __syncthreads();
            int validc = M - (m0 + ch * 64); if (validc > 64) validc = 64;
            if (tid < BM && rt * BM + tid < QROWS) {
                for (int c = 0; c < validc; ++c) {
                    float v = Cs[tid * CSTRIDE + c];
                    if (v > t4) {
                        t4 = v;
                        if (t4 > t3) { float tmp = t3; t3 = t4; t4 = tmp; }
                        if (t3 > t2) { float tmp = t2; t2 = t3; t3 = tmp; }
                        if (t2 > t1) { float tmp = t1; t1 = t2; t2 = tmp; }
                        if (t1 > t0) { float tmp = t0; t0 = t1; t1 = tmp; }
                    }
                }
            }
            __syncthreads();
        }
    }

    if (tid < BM) {
        int grow = rt * BM + tid;
        if (grow < QROWS) {
            int q = grow / HW;
            atomicAdd(&ws[WS_FEAT + (b * Q + q) * 10 + 5 + w],
                      (t0 + t1 + t2 + t3 + t4) * (1.f / M));
        }
    }
}

// ---------------- kernel 5: BatchNorm (training stats over q) + dilated conv ---
__global__ void bn_conv_kernel(const float* __restrict__ gamma, const float* __restrict__ beta,
                               const float* __restrict__ convw, const float* __restrict__ wsr,
                               float* __restrict__ out) {
    __shared__ float mu[10], rstd[10];
    int b = blockIdx.x;
    const float* feat = wsr + WS_FEAT + b * Q * 10;
    int t = threadIdx.x;
    if (t < 10) {
        float s = 0.f;
        for (int q = 0; q < Q; ++q) s += feat[q * 10 + t];
        float m = s / Q;
        float ss = 0.f;
        for (int q = 0; q < Q; ++q) { float d = feat[q * 10 + t] - m; ss += d * d; }
        mu[t] = m;
        rstd[t] = rsqrtf(ss / Q + 1e-5f);   // biased var, two-pass
    }
    __syncthreads();
    if (t < Q * WAY) {
        int q = t / WAY, j = t % WAY;
        float bn0 = (feat[q * 10 + j]     - mu[j])     * rstd[j]     * gamma[j]     + beta[j];
        float bn1 = (feat[q * 10 + 5 + j] - mu[5 + j]) * rstd[5 + j] * gamma[5 + j] + beta[5 + j];
        out[(b * Q + q) * WAY + j] = convw[0] * bn0 + convw[1] * bn1;
    }
}

extern "C" void kernel_launch(void* const* d_in, const int* in_sizes, int n_in,
                              void* d_out, int out_size, void* d_ws, size_t ws_size,
                              hipStream_t stream) {
    const float* xq    = (const float*)d_in[0];
    const float* xs    = (const float*)d_in[1];
    const float* gamma = (const float*)d_in[2];
    const float* beta  = (const float*)d_in[3];
    const float* convw = (const float*)d_in[4];
    float* ws  = (float*)d_ws;
    float* out = (float*)d_out;

    norms_kernel<<<(NDQ + NDS + 3) / 4, 256, 0, stream>>>(xq, xs, ws);
    means_kernel<<<BB * Q + BB * WAY, 256, 0, stream>>>(xq, xs, ws);
    cos_kernel<<<(BB * Q * WAY + 3) / 4, 256, 0, stream>>>(ws);
    dn4_kernel<<<BB * WAY * NRT, 256, 0, stream>>>(xq, xs, ws);
    bn_conv_kernel<<<BB, 384, 0, stream>>>(gamma, beta, convw, ws, out);
}

// Round 4
// 860.112 us; speedup vs baseline: 6.0741x; 1.0648x over previous
//
#include <hip/hip_runtime.h>

// Problem constants (fixed by setup_inputs)
#define BB 4
#define Q 75
#define WAY 5
#define HW 100
#define D 640
#define M 500          // shot*HW
#define QROWS 7500     // Q*HW
#define NDQ 30000      // BB*QROWS query descriptors

// ws layout: floats at low offsets, pre-split B arrays at byte offsets.
// TOTAL ws ask: ~27.3 MB (WS_BL_BYTE + 13.1 MB).
#define WS_QINV 0
#define WS_SINV 30000
#define WS_QMEAN 40000     // BB*Q*D = 192000
#define WS_PROTO 232000    // BB*WAY*D = 12800
#define WS_FEAT 244800     // BB*Q*10 = 3000
#define WS_BH_BYTE 1048576u               // 20*32*20*1024 = 13107200 B
#define WS_BL_BYTE (1048576u + 13107200u)

using short8  = __attribute__((ext_vector_type(8))) short;
using short4v = __attribute__((ext_vector_type(4))) short;
using float4v = __attribute__((ext_vector_type(4))) float;

#define GLOBAL_LOAD_LDS16(g, l)                                                   \
    __builtin_amdgcn_global_load_lds(                                             \
        (const __attribute__((address_space(1))) unsigned int*)(g),               \
        (__attribute__((address_space(3))) unsigned int*)(l), 16, 0, 0)

__device__ __forceinline__ void split1(float v, unsigned short& h, unsigned short& l) {
    unsigned u = __float_as_uint(v);
    unsigned short hu = (unsigned short)(u >> 16);          // truncate to bf16
    float hf = __uint_as_float((unsigned)hu << 16);
    float lo = v - hf;                                       // exact residual
    unsigned short lu = (unsigned short)(__float_as_uint(lo) >> 16);
    h = hu; l = lu;
}

__device__ __forceinline__ void split_store(float4 v, float s, short* dh, short* dl) {
    unsigned short h0,h1,h2,h3,l0,l1,l2,l3;
    split1(v.x * s, h0, l0); split1(v.y * s, h1, l1);
    split1(v.z * s, h2, l2); split1(v.w * s, h3, l3);
    short4v hv, lv;
    hv[0]=(short)h0; hv[1]=(short)h1; hv[2]=(short)h2; hv[3]=(short)h3;
    lv[0]=(short)l0; lv[1]=(short)l1; lv[2]=(short)l2; lv[3]=(short)l3;
    *(short4v*)dh = hv;
    *(short4v*)dl = lv;
}

// ---------------- kernel 0: pre-split B (normalize + bf16 hi/lo, frag-order) ---
// block = (bw, rf): 16 support rows x 640 k. Output frag layout:
// byte = ((bw*32+rf)*20 + kt)*1024 + (kg*16 + rho)*16 + j*2   (lane = kg*16+rho)
__global__ __launch_bounds__(256) void presplit_b(const float* __restrict__ xs,
                                                  float* __restrict__ ws) {
    __shared__ float partial[256];
    __shared__ float sinvS[16];
    __shared__ short Sh[16][648];
    __shared__ short Sl[16][648];
    int bw = blockIdx.x >> 5;      // 0..19
    int rf = blockIdx.x & 31;      // 0..31
    int tid = threadIdx.x;
    int rho = tid & 15;
    int kc  = tid >> 4;            // 0..15, covers k in [kc*40, kc*40+40)
    int m = rf * 16 + rho;
    bool valid = (m < M);
    const float* src = xs + ((size_t)bw * M + m) * D + kc * 40;

    float4 v[10];
    float ss = 0.f;
    #pragma unroll
    for (int i = 0; i < 10; ++i) {
        v[i] = valid ? *(const float4*)(src + i * 4) : make_float4(0.f,0.f,0.f,0.f);
        ss += v[i].x*v[i].x + v[i].y*v[i].y + v[i].z*v[i].z + v[i].w*v[i].w;
    }
    partial[tid] = ss;
    __syncthreads();
    if (tid < 16) {
        float sum = 0.f;
        #pragma unroll
        for (int k = 0; k < 16; ++k) sum += partial[k * 16 + tid];
        float inv = (sum > 0.f) ? rsqrtf(sum) : 0.f;
        sinvS[tid] = inv;
        int mm = rf * 16 + tid;
        if (mm < M) ws[WS_SINV + bw * M + mm] = inv;
    }
    __syncthreads();
    float s = sinvS[rho];
    #pragma unroll
    for (int i = 0; i < 10; ++i) {
        int k = kc * 40 + i * 4;
        split_store(v[i], s, &Sh[rho][k], &Sl[rho][k]);
    }
    __syncthreads();
    // output: wave wv handles kt = wv*5 + p
    int lane = tid & 63, wv = tid >> 6;
    int rs = lane & 15, kg = lane >> 4;
    char* wsb = (char*)ws;
    #pragma unroll
    for (int p = 0; p < 5; ++p) {
        int kt = wv * 5 + p;
        short8 hv = *(const short8*)&Sh[rs][kt * 32 + kg * 8];
        short8 lv = *(const short8*)&Sl[rs][kt * 32 + kg * 8];
        size_t fo = ((size_t)(bw * 32 + rf) * 20 + kt) * 1024 + lane * 16;
        *(short8*)(wsb + WS_BH_BYTE + fo) = hv;
        *(short8*)(wsb + WS_BL_BYTE + fo) = lv;
    }
}

// ---------------- kernel 1: inverse L2 norms of query descriptors --------------
__global__ void norms_kernel(const float* __restrict__ xq, float* __restrict__ ws) {
    int wid  = (int)((blockIdx.x * blockDim.x + threadIdx.x) >> 6);
    int lane = threadIdx.x & 63;
    if (wid >= NDQ) return;
    const float* p = xq + (size_t)wid * D;
    float s = 0.f;
    #pragma unroll
    for (int j = 0; j < D; j += 64) { float v = p[j + lane]; s += v * v; }
    for (int off = 32; off; off >>= 1) s += __shfl_down(s, off);
    if (lane == 0) ws[WS_QINV + wid] = rsqrtf(s);
}

// ---------------- kernel 2: query_mean (over HW) and proto (over shot*HW) ------
__global__ void means_kernel(const float* __restrict__ xq, const float* __restrict__ xs,
                             float* __restrict__ ws) {
    __shared__ float inv[M];
    int bid = blockIdx.x;
    if (bid < BB * Q) {
        for (int i = threadIdx.x; i < HW; i += blockDim.x) inv[i] = ws[WS_QINV + bid * HW + i];
        __syncthreads();
        const float* base = xq + (size_t)bid * HW * D;
        for (int d = threadIdx.x; d < D; d += blockDim.x) {
            float s = 0.f;
            for (int h = 0; h < HW; ++h) s += base[(size_t)h * D + d] * inv[h];
            ws[WS_QMEAN + bid * D + d] = s * (1.f / HW);
        }
    } else {
        int bw = bid - BB * Q; // 0..19
        for (int i = threadIdx.x; i < M; i += blockDim.x) inv[i] = ws[WS_SINV + bw * M + i];
        __syncthreads();
        const float* base = xs + (size_t)bw * M * D;
        for (int d = threadIdx.x; d < D; d += blockDim.x) {
            float s = 0.f;
            for (int m = 0; m < M; ++m) s += base[(size_t)m * D + d] * inv[m];
            ws[WS_PROTO + bw * D + d] = s * (1.f / M);
        }
    }
}

// ---------------- kernel 3: cosine-prototype logits + zero-init sim slots ------
__global__ void cos_kernel(float* __restrict__ ws) {
    int idx  = (int)((blockIdx.x * blockDim.x + threadIdx.x) >> 6);
    int lane = threadIdx.x & 63;
    if (idx >= BB * Q * WAY) return;
    int w = idx % WAY; int bq = idx / WAY; int b = bq / Q;
    const float* qm = ws + WS_QMEAN + bq * D;
    const float* pr = ws + WS_PROTO + (b * WAY + w) * D;
    float s = 0.f;
    #pragma unroll
    for (int j = 0; j < D; j += 64) s += qm[j + lane] * pr[j + lane];
    for (int off = 32; off; off >>= 1) s += __shfl_down(s, off);
    if (lane == 0) {
        ws[WS_FEAT + bq * 10 + w]     = s;
        ws[WS_FEAT + bq * 10 + 5 + w] = 0.f;
    }
}

// ---------------- kernel 4: MFMA split-bf16 GEMM + streaming top-5 -------------
// 128 rows x 128-col chunks (mc 0..3), 4 waves 2x2 (64x64 each), BK=32.
// Frag-order LDS; B staged via global_load_lds from pre-split ws; dbuf, 1 barrier/kt.
#define BM 128
#define NRT 59        // ceil(7500/128)
#define BUFSZ 32768   // per-buffer: Ah 8K | Al 8K | Bh 8K | Bl 8K
#define CSTRIDE 65

__global__ __launch_bounds__(256) void dn4_kernel(const float* __restrict__ xq,
                                                  const float* __restrict__ ws_ro,
                                                  float* __restrict__ ws) {
    __shared__ __align__(16) char smem[65536];   // 2 buffers; Cs scan unions low bytes
    float* Cs = (float*)smem;

    int bid = blockIdx.x;
    int rt = bid % NRT; int bw = bid / NRT;
    int w = bw % WAY;   int b  = bw / WAY;
    int tid  = threadIdx.x;
    int lane = tid & 63;
    int wave = tid >> 6;
    int wr = wave >> 1, wc = wave & 1;
    int lfree = lane & 15;
    int lq    = lane >> 4;

    // per-lane frag-read byte offsets (within a buffer)
    int a_slot = (lq * 16 + (lfree ^ (lq << 2))) * 16;   // kg-XOR swizzle
    int b_slot = lane * 16;                               // canonical (DMA order)

    // A prefetch setup: rep r covers tile-row rep*32 + (tid>>3), k0 = (tid&7)*4
    const int c8 = tid & 7;
    const int k0 = c8 * 4;
    const float* aptr[4];
    float qv[4];
    int adst[4];
    #pragma unroll
    for (int rep = 0; rep < 4; ++rep) {
        int rowt = rep * 32 + (tid >> 3);        // 0..127
        int grow = rt * BM + rowt;
        bool ok = grow < QROWS;
        aptr[rep] = ok ? (xq + ((size_t)b * QROWS + grow) * D + k0) : xq;
        qv[rep]   = ok ? ws_ro[WS_QINV + b * QROWS + grow] : 0.f;
        int rf = rowt >> 4, rho = rowt & 15, kg = k0 >> 3;
        int slot = kg * 16 + (rho ^ (kg << 2));
        adst[rep] = rf * 1024 + slot * 16 + (k0 & 7) * 2;
    }
    const char* wsb = (const char*)ws_ro;
    const char* bh_g = wsb + WS_BH_BYTE;
    const char* bl_g = wsb + WS_BL_BYTE;

    float t0 = -1e30f, t1 = -1e30f, t2 = -1e30f, t3 = -1e30f, t4 = -1e30f;

    for (int mc = 0; mc < 4; ++mc) {
        int m0 = mc * 128;
        float4v acc[4][4];
        #pragma unroll
        for (int jj = 0; jj < 4; ++jj)
            #pragma unroll
            for (int ii = 0; ii < 4; ++ii) {
                acc[jj][ii][0]=0.f; acc[jj][ii][1]=0.f; acc[jj][ii][2]=0.f; acc[jj][ii][3]=0.f;
            }
        __syncthreads();   // scan reads (prev mc) done before restage

        float4 pf[4];

        // ---- stage helpers (macros for static buffer index) ----
        #define STAGE_B(nbuf, kt) {                                                        \
            _Pragma("unroll")                                                              \
            for (int u = 0; u < 4; ++u) {                                                  \
                int fi = wave * 4 + u;            /* 0..15 */                              \
                int hl = fi >> 3;                 /* 0=hi 1=lo */                          \
                int cf = fi & 7;                                                           \
                const char* g = (hl ? bl_g : bh_g)                                         \
                    + ((size_t)((bw * 32 + mc * 8 + cf) * 20 + (kt))) * 1024 + lane * 16;  \
                GLOBAL_LOAD_LDS16(g, smem + (nbuf) * BUFSZ + 16384 + hl * 8192 + cf * 1024);\
            }                                                                              \
        }
        #define LOAD_A(kt) {                                                               \
            _Pragma("unroll")                                                              \
            for (int rep = 0; rep < 4; ++rep)                                              \
                pf[rep] = *(const float4*)(aptr[rep] + (kt) * 32);                         \
        }
        #define STORE_A(nbuf) {                                                            \
            _Pragma("unroll")                                                              \
            for (int rep = 0; rep < 4; ++rep)                                              \
                split_store(pf[rep], qv[rep],                                              \
                            (short*)(smem + (nbuf) * BUFSZ + adst[rep]),                   \
                            (short*)(smem + (nbuf) * BUFSZ + 8192 + adst[rep]));           \
        }
        #define COMPUTE(nbuf) {                                                            \
            short8 ahf[4], alf[4], bhf[4], blf[4];                                         \
            _Pragma("unroll")                                                              \
            for (int jj = 0; jj < 4; ++jj) {                                               \
                int rf = 4 * wr + jj;                                                      \
                ahf[jj] = *(const short8*)(smem + (nbuf) * BUFSZ + rf * 1024 + a_slot);    \
                alf[jj] = *(const short8*)(smem + (nbuf) * BUFSZ + 8192 + rf * 1024 + a_slot);\
            }                                                                              \
            _Pragma("unroll")                                                              \
            for (int ii = 0; ii < 4; ++ii) {                                               \
                int cf = 4 * wc + ii;                                                      \
                bhf[ii] = *(const short8*)(smem + (nbuf) * BUFSZ + 16384 + cf * 1024 + b_slot);\
                blf[ii] = *(const short8*)(smem + (nbuf) * BUFSZ + 24576 + cf * 1024 + b_slot);\
            }                                                                              \
            _Pragma("unroll")                                                              \
            for (int jj = 0; jj < 4; ++jj)                                                 \
                _Pragma("unroll")                                                          \
                for (int ii = 0; ii < 4; ++ii) {                                           \
                    acc[jj][ii] = __builtin_amdgcn_mfma_f32_16x16x32_bf16(ahf[jj], bhf[ii], acc[jj][ii], 0, 0, 0); \
                    acc[jj][ii] = __builtin_amdgcn_mfma_f32_16x16x32_bf16(ahf[jj], blf[ii], acc[jj][ii], 0, 0, 0); \
                    acc[jj][ii] = __builtin_amdgcn_mfma_f32_16x16x32_bf16(alf[jj], bhf[ii], acc[jj][ii], 0, 0, 0); \
                }                                                                          \
        }

        // prologue: stage kt=0 into buf0
        STAGE_B(0, 0);
        LOAD_A(0);
        STORE_A(0);
        __syncthreads();

        #pragma unroll
        for (int kp = 0; kp < 10; ++kp) {
            {   // even kt: compute buf0, stage kt+1 into buf1
                int kt = kp * 2;
                STAGE_B(1, kt + 1);
                LOAD_A(kt + 1);
                COMPUTE(0);
                STORE_A(1);
                __syncthreads();
            }
            {   // odd kt: compute buf1, stage kt+2 into buf0
                int kt = kp * 2 + 1;
                if (kt < 19) {
                    STAGE_B(0, kt + 1);
                    LOAD_A(kt + 1);
                }
                COMPUTE(1);
                if (kt < 19) STORE_A(0);
                __syncthreads();
            }
        }

        // ---- scan in two 64-col halves (C/D layout: col=lane&15, row=quad*4+reg)
        #pragma unroll
        for (int ch = 0; ch < 2; ++ch) {
            if (wc == ch) {
                #pragma unroll
                for (int jj = 0; jj < 4; ++jj)
                    #pragma unroll
                    for (int ii = 0; ii < 4; ++ii) {
                        int rbase = 64 * wr + 16 * jj + lq * 4;
                        int col   = 16 * ii + lfree;
                        #pragma unroll
                        for (int r = 0; r < 4; ++r)
                            Cs[(rbase + r) * CSTRIDE + col] = acc[jj][ii][r];
                    }
            }
            __syncthreads();
            int validc = M - (m0 + ch * 64); if (validc > 64) validc = 64;
            if (tid < BM && rt * BM + tid < QROWS) {
                for (int c = 0; c < validc; ++c) {
                    float v = Cs[tid * CSTRIDE + c];
                    if (v > t4) {
                        t4 = v;
                        if (t4 > t3) { float tmp = t3; t3 = t4; t4 = tmp; }
                        if (t3 > t2) { float tmp = t2; t2 = t3; t3 = tmp; }
                        if (t2 > t1) { float tmp = t1; t1 = t2; t2 = tmp; }
                        if (t1 > t0) { float tmp = t0; t0 = t1; t1 = tmp; }
                    }
                }
            }
            __syncthreads();
        }
    }

    if (tid < BM) {
        int grow = rt * BM + tid;
        if (grow < QROWS) {
            int q = grow / HW;
            atomicAdd(&ws[WS_FEAT + (b * Q + q) * 10 + 5 + w],
                      (t0 + t1 + t2 + t3 + t4) * (1.f / M));
        }
    }
}

// ---------------- kernel 5: BatchNorm (training stats over q) + dilated conv ---
__global__ void bn_conv_kernel(const float* __restrict__ gamma, const float* __restrict__ beta,
                               const float* __restrict__ convw, const float* __restrict__ wsr,
                               float* __restrict__ out) {
    __shared__ float mu[10], rstd[10];
    int b = blockIdx.x;
    const float* feat = wsr + WS_FEAT + b * Q * 10;
    int t = threadIdx.x;
    if (t < 10) {
        float s = 0.f;
        for (int q = 0; q < Q; ++q) s += feat[q * 10 + t];
        float m = s / Q;
        float ss = 0.f;
        for (int q = 0; q < Q; ++q) { float d = feat[q * 10 + t] - m; ss += d * d; }
        mu[t] = m;
        rstd[t] = rsqrtf(ss / Q + 1e-5f);
    }
    __syncthreads();
    if (t < Q * WAY) {
        int q = t / WAY, j = t % WAY;
        float bn0 = (feat[q * 10 + j]     - mu[j])     * rstd[j]     * gamma[j]     + beta[j];
        float bn1 = (feat[q * 10 + 5 + j] - mu[5 + j]) * rstd[5 + j] * gamma[5 + j] + beta[5 + j];
        out[(b * Q + q) * WAY + j] = convw[0] * bn0 + convw[1] * bn1;
    }
}

extern "C" void kernel_launch(void* const* d_in, const int* in_sizes, int n_in,
                              void* d_out, int out_size, void* d_ws, size_t ws_size,
                              hipStream_t stream) {
    const float* xq    = (const float*)d_in[0];
    const float* xs    = (const float*)d_in[1];
    const float* gamma = (const float*)d_in[2];
    const float* beta  = (const float*)d_in[3];
    const float* convw = (const float*)d_in[4];
    float* ws  = (float*)d_ws;
    float* out = (float*)d_out;

    presplit_b<<<20 * 32, 256, 0, stream>>>(xs, ws);            // sinv + frag-order B
    norms_kernel<<<(NDQ + 3) / 4, 256, 0, stream>>>(xq, ws);    // qinv
    means_kernel<<<BB * Q + BB * WAY, 256, 0, stream>>>(xq, xs, ws);
    cos_kernel<<<(BB * Q * WAY + 3) / 4, 256, 0, stream>>>(ws);
    dn4_kernel<<<BB * WAY * NRT, 256, 0, stream>>>(xq, ws, ws);
    bn_conv_kernel<<<BB, 384, 0, stream>>>(gamma, beta, convw, ws, out);
}